// Round 5
// baseline (523.935 us; speedup 1.0000x reference)
//
#include <hip/hip_runtime.h>
#include <hip/hip_bf16.h>
#include <cstdint>
#include <cstddef>

#define K2V 36864   // (3*64)^2
#define MN  1024    // nodes
#define HF  768     // HORIZON * H_FSIZE
#define NKC 576     // K2V / 64 kchunks
#define TILE_SH 8192  // 128x64 bf16 tile, shorts

typedef __attribute__((ext_vector_type(8))) short short8;   // 8 bf16
typedef __attribute__((ext_vector_type(4))) float f32x4;    // MFMA acc

typedef __attribute__((address_space(3))) void lvoid;
typedef __attribute__((address_space(1))) const void gvoid;

__device__ __forceinline__ unsigned pk_bf2(float a, float b) {
    __hip_bfloat16 ha = __float2bfloat16(a);
    __hip_bfloat16 hb = __float2bfloat16(b);
    unsigned short ua = *reinterpret_cast<unsigned short*>(&ha);
    unsigned short ub = *reinterpret_cast<unsigned short*>(&hb);
    return (unsigned)ua | ((unsigned)ub << 16);
}

__device__ __forceinline__ void gl_lds16(const unsigned short* g, unsigned short* l) {
    __builtin_amdgcn_global_load_lds((gvoid*)g, (lvoid*)l, 16, 0, 0);
}

// ---------------------------------------------------------------------------
// Pass 0: convert f32 A (1024xK) and B (768xK) to bf16 tiles of 128x64,
// laid out EXACTLY as the GEMM's LDS wants them: linear gload_lds dest +
// XOR-swizzle pre-applied to the byte offset (rule #21 / m201 pattern).
// Tile (panel p, kchunk kc) lives at (p*NKC + kc)*TILE_SH shorts.
// ---------------------------------------------------------------------------
__global__ __launch_bounds__(256)
void convert_tiles(const float* __restrict__ A, const float* __restrict__ B,
                   unsigned short* __restrict__ dst)
{
    const int b = blockIdx.x;
    const float* src;
    unsigned short* out;
    if (b < 8 * NKC) {                       // A tiles: 8 panels
        const int mt = b / NKC, kc = b - mt * NKC;
        src = A + (size_t)(mt * 128) * K2V + kc * 64;
        out = dst + (size_t)b * TILE_SH;
    } else {                                 // B tiles: 6 panels
        const int bb = b - 8 * NKC;
        const int nt = bb / NKC, kc = bb - nt * NKC;
        src = B + (size_t)(nt * 128) * K2V + kc * 64;
        out = dst + (size_t)b * TILE_SH;     // B starts right after A region
    }
    const int c8 = threadIdx.x & 7;          // 8-col group (16B bf16)
    const int r0 = threadIdx.x >> 3;         // 0..31
    #pragma unroll
    for (int i = 0; i < 4; ++i) {
        const int r = r0 + 32 * i;
        const float* p = src + (size_t)r * K2V + c8 * 8;
        const float4 v0 = *reinterpret_cast<const float4*>(p);
        const float4 v1 = *reinterpret_cast<const float4*>(p + 4);
        uint4 w = { pk_bf2(v0.x, v0.y), pk_bf2(v0.z, v0.w),
                    pk_bf2(v1.x, v1.y), pk_bf2(v1.z, v1.w) };
        const int off = (r * 128 + c8 * 16) ^ ((r & 7) << 4);   // pre-swizzled
        *reinterpret_cast<uint4*>(reinterpret_cast<char*>(out) + off) = w;
    }
}

// ---------------------------------------------------------------------------
// Stage 1 (bf16 path): part[ks][1024][768] = A @ B^T partials.
// 128x128 tile, BK=64, 8 waves, global_load_lds(16B) staging, double-buffered,
// counted vmcnt(4) across raw barriers (T4: never drain to 0 mid-loop).
// ---------------------------------------------------------------------------
__global__ __launch_bounds__(512, 4)
void gemm_bf16(const unsigned short* __restrict__ Abf,
               const unsigned short* __restrict__ Bbf,
               float* __restrict__ part, int NSTEP)
{
    __shared__ unsigned short sA[2][TILE_SH];   // 2 x 16KB
    __shared__ unsigned short sB[2][TILE_SH];   // 2 x 16KB

    const int tid  = threadIdx.x;
    const int lane = tid & 63;
    const int wave = tid >> 6;
    const int wm   = wave >> 2;   // 0..1
    const int wn   = wave & 3;    // 0..3

    int mtile, ntile, kidx;
    if ((gridDim.x & 7) == 0) {               // XCD-chunked: mtile == XCD
        mtile = blockIdx.x & 7;
        const int pos = blockIdx.x >> 3;
        kidx  = pos / 6;
        ntile = pos - kidx * 6;
    } else {
        kidx = blockIdx.x / 48;
        const int rem = blockIdx.x - kidx * 48;
        mtile = rem / 6;
        ntile = rem - mtile * 6;
    }

    const unsigned short* At = Abf + ((size_t)mtile * NKC + kidx * NSTEP) * TILE_SH;
    const unsigned short* Bt = Bbf + ((size_t)ntile * NKC + kidx * NSTEP) * TILE_SH;

    f32x4 acc[4][2];
    #pragma unroll
    for (int i = 0; i < 4; ++i)
        #pragma unroll
        for (int j = 0; j < 2; ++j)
            acc[i][j] = (f32x4){0.f, 0.f, 0.f, 0.f};

    auto stage = [&](int s, int buf) {        // 4 gload_lds instrs / thread
        const unsigned short* ga = At + (size_t)s * TILE_SH + tid * 8;
        const unsigned short* gb = Bt + (size_t)s * TILE_SH + tid * 8;
        gl_lds16(ga,        &sA[buf][tid * 8]);
        gl_lds16(ga + 4096, &sA[buf][4096 + tid * 8]);
        gl_lds16(gb,        &sB[buf][tid * 8]);
        gl_lds16(gb + 4096, &sB[buf][4096 + tid * 8]);
    };

    auto compute = [&](int buf) {
        #pragma unroll
        for (int ks = 0; ks < 2; ++ks) {
            short8 av[4], bv[2];
            const int cb = (ks * 32 + (lane >> 4) * 8) * 2;
            #pragma unroll
            for (int i = 0; i < 4; ++i) {
                const int rA = wm * 64 + i * 16 + (lane & 15);
                const int oa = (rA * 128 + cb) ^ ((rA & 7) << 4);
                av[i] = *reinterpret_cast<const short8*>(
                          reinterpret_cast<const char*>(sA[buf]) + oa);
            }
            #pragma unroll
            for (int j = 0; j < 2; ++j) {
                const int rB = wn * 32 + j * 16 + (lane & 15);
                const int ob = (rB * 128 + cb) ^ ((rB & 7) << 4);
                bv[j] = *reinterpret_cast<const short8*>(
                          reinterpret_cast<const char*>(sB[buf]) + ob);
            }
            #pragma unroll
            for (int i = 0; i < 4; ++i)
                #pragma unroll
                for (int j = 0; j < 2; ++j)
                    acc[i][j] = __builtin_amdgcn_mfma_f32_16x16x32_bf16(av[i], bv[j], acc[i][j], 0, 0, 0);
        }
    };

    // prologue: fill both buffers; wait only for buf0 (leave buf1 in flight)
    stage(0, 0);
    stage(1, 1);
    asm volatile("s_waitcnt vmcnt(4)" ::: "memory");
    __builtin_amdgcn_s_barrier();

    for (int s = 0; s < NSTEP - 2; ++s) {
        const int buf = s & 1;
        compute(buf);
        asm volatile("s_waitcnt lgkmcnt(0)" ::: "memory");   // my ds_reads done
        __builtin_amdgcn_s_barrier();                        // all waves done with buf
        stage(s + 2, buf);                                   // refill buf
        asm volatile("s_waitcnt vmcnt(4)" ::: "memory");     // s+1 loads landed
        __builtin_amdgcn_s_barrier();                        // everyone's s+1 landed
    }
    {   // s = NSTEP-2: nothing left to stage; drain for last buffer
        compute((NSTEP - 2) & 1);
        asm volatile("s_waitcnt lgkmcnt(0)" ::: "memory");
        __builtin_amdgcn_s_barrier();
        asm volatile("s_waitcnt vmcnt(0)" ::: "memory");
        __builtin_amdgcn_s_barrier();
        compute((NSTEP - 1) & 1);
    }

    // C/D: col = lane&15, row = (lane>>4)*4 + q  [m89/m91]
    float* P = part + ((size_t)kidx * MN + mtile * 128 + wm * 64) * HF
                    + ntile * 128 + wn * 32;
    #pragma unroll
    for (int i = 0; i < 4; ++i) {
        #pragma unroll
        for (int j = 0; j < 2; ++j) {
            const int col = j * 16 + (lane & 15);
            #pragma unroll
            for (int q = 0; q < 4; ++q) {
                const int row = i * 16 + (lane >> 4) * 4 + q;
                P[(size_t)row * HF + col] = acc[i][j][q];
            }
        }
    }
}

// ---------------------------------------------------------------------------
// Fallback Stage 1 (f32 path, R2 kernel): used when ws can't hold bf16 copies.
// ---------------------------------------------------------------------------
__global__ __launch_bounds__(512, 4)
void gemm_h_split(const float* __restrict__ A, const float* __restrict__ B,
                  float* __restrict__ part, int KC)
{
    __shared__ unsigned short sA[2][128 * 64];
    __shared__ unsigned short sB[2][128 * 64];

    const int tid  = threadIdx.x;
    const int lane = tid & 63;
    const int wave = tid >> 6;
    const int wm   = wave >> 2;
    const int wn   = wave & 3;

    int mtile, ntile, kidx;
    if ((gridDim.x & 7) == 0) {
        mtile = blockIdx.x & 7;
        const int pos = blockIdx.x >> 3;
        kidx  = pos / 6;
        ntile = pos - kidx * 6;
    } else {
        kidx = blockIdx.x / 48;
        const int rem = blockIdx.x - kidx * 48;
        mtile = rem / 6;
        ntile = rem - mtile * 6;
    }
    const int k0 = kidx * KC;

    const float* Ap = A + (size_t)(mtile * 128) * K2V + k0;
    const float* Bp = B + (size_t)(ntile * 128) * K2V + k0;

    const int c4 = tid & 15;
    const int r0 = tid >> 4;

    f32x4 acc[4][2];
    #pragma unroll
    for (int i = 0; i < 4; ++i)
        #pragma unroll
        for (int j = 0; j < 2; ++j)
            acc[i][j] = (f32x4){0.f, 0.f, 0.f, 0.f};

    float4 ra[4], rb[4];
    auto load_step = [&](int s) {
        const float* a = Ap + s * 64 + c4 * 4;
        const float* b = Bp + s * 64 + c4 * 4;
        #pragma unroll
        for (int i = 0; i < 4; ++i) {
            const int r = r0 + 32 * i;
            ra[i] = *reinterpret_cast<const float4*>(a + (size_t)r * K2V);
            rb[i] = *reinterpret_cast<const float4*>(b + (size_t)r * K2V);
        }
    };
    auto write_step = [&](int buf) {
        #pragma unroll
        for (int i = 0; i < 4; ++i) {
            const int r = r0 + 32 * i;
            int off = r * 128 + c4 * 8;
            off ^= (r & 7) << 4;
            uint2 va = { pk_bf2(ra[i].x, ra[i].y), pk_bf2(ra[i].z, ra[i].w) };
            uint2 vb = { pk_bf2(rb[i].x, rb[i].y), pk_bf2(rb[i].z, rb[i].w) };
            *reinterpret_cast<uint2*>(reinterpret_cast<char*>(sA[buf]) + off) = va;
            *reinterpret_cast<uint2*>(reinterpret_cast<char*>(sB[buf]) + off) = vb;
        }
    };

    const int nsteps = KC >> 6;
    load_step(0);
    write_step(0);
    __syncthreads();

    for (int s = 0; s < nsteps; ++s) {
        if (s + 1 < nsteps) load_step(s + 1);
        const int buf = s & 1;
        #pragma unroll
        for (int ks = 0; ks < 2; ++ks) {
            short8 av[4], bv[2];
            const int cb = (ks * 32 + (lane >> 4) * 8) * 2;
            #pragma unroll
            for (int i = 0; i < 4; ++i) {
                const int rA = wm * 64 + i * 16 + (lane & 15);
                int oa = rA * 128 + cb; oa ^= (rA & 7) << 4;
                av[i] = *reinterpret_cast<const short8*>(reinterpret_cast<const char*>(sA[buf]) + oa);
            }
            #pragma unroll
            for (int j = 0; j < 2; ++j) {
                const int rB = wn * 32 + j * 16 + (lane & 15);
                int ob = rB * 128 + cb; ob ^= (rB & 7) << 4;
                bv[j] = *reinterpret_cast<const short8*>(reinterpret_cast<const char*>(sB[buf]) + ob);
            }
            #pragma unroll
            for (int i = 0; i < 4; ++i)
                #pragma unroll
                for (int j = 0; j < 2; ++j)
                    acc[i][j] = __builtin_amdgcn_mfma_f32_16x16x32_bf16(av[i], bv[j], acc[i][j], 0, 0, 0);
        }
        if (s + 1 < nsteps) write_step((s + 1) & 1);
        __syncthreads();
    }

    float* P = part + ((size_t)kidx * MN + mtile * 128 + wm * 64) * HF
                    + ntile * 128 + wn * 32;
    #pragma unroll
    for (int i = 0; i < 4; ++i) {
        #pragma unroll
        for (int j = 0; j < 2; ++j) {
            const int col = j * 16 + (lane & 15);
            #pragma unroll
            for (int q = 0; q < 4; ++q) {
                const int row = i * 16 + (lane >> 4) * 4 + q;
                P[(size_t)row * HF + col] = acc[i][j][q];
            }
        }
    }
}

// Stage 2a: reduce split-K partials + bias, in place into part slice 0.
__global__ __launch_bounds__(256)
void h_reduce(float* __restrict__ part, const float* __restrict__ bias, int ksplit)
{
    const int fidx = blockIdx.x * 256 + threadIdx.x;
    const int n  = fidx / 192;
    const int j4 = fidx - n * 192;
    const size_t base = (size_t)n * HF + j4 * 4;
    const size_t kstride = (size_t)MN * HF;

    float4 s0 = *reinterpret_cast<const float4*>(bias + j4 * 4);
    float4 s1 = {0.f,0.f,0.f,0.f}, s2 = {0.f,0.f,0.f,0.f}, s3 = {0.f,0.f,0.f,0.f};
    int k = 0;
    for (; k + 4 <= ksplit; k += 4) {
        float4 p0 = *reinterpret_cast<const float4*>(part + (size_t)(k + 0) * kstride + base);
        float4 p1 = *reinterpret_cast<const float4*>(part + (size_t)(k + 1) * kstride + base);
        float4 p2 = *reinterpret_cast<const float4*>(part + (size_t)(k + 2) * kstride + base);
        float4 p3 = *reinterpret_cast<const float4*>(part + (size_t)(k + 3) * kstride + base);
        s0.x += p0.x; s0.y += p0.y; s0.z += p0.z; s0.w += p0.w;
        s1.x += p1.x; s1.y += p1.y; s1.z += p1.z; s1.w += p1.w;
        s2.x += p2.x; s2.y += p2.y; s2.z += p2.z; s2.w += p2.w;
        s3.x += p3.x; s3.y += p3.y; s3.z += p3.z; s3.w += p3.w;
    }
    for (; k < ksplit; ++k) {
        float4 p0 = *reinterpret_cast<const float4*>(part + (size_t)k * kstride + base);
        s0.x += p0.x; s0.y += p0.y; s0.z += p0.z; s0.w += p0.w;
    }
    float4 r;
    r.x = (s0.x + s1.x) + (s2.x + s3.x);
    r.y = (s0.y + s1.y) + (s2.y + s3.y);
    r.z = (s0.z + s1.z) + (s2.z + s3.z);
    r.w = (s0.w + s1.w) + (s2.w + s3.w);
    *reinterpret_cast<float4*>(part + base) = r;
}

// Stage 2b: out[b,t,n] = sum_f x[b,f] * h[n,t*64+f]
__global__ __launch_bounds__(256)
void hyper_out(const float* __restrict__ xall, const float* __restrict__ hred,
               float* __restrict__ out)
{
    const int n   = blockIdx.x;
    const int tid = threadIdx.x;
    __shared__ float hs[HF];
    __shared__ float xs[64 * 65];

    #pragma unroll
    for (int jj = 0; jj < 3; ++jj) {
        const int j = tid + jj * 256;
        hs[j] = hred[(size_t)n * HF + j];
    }
    {
        const int c4 = tid & 15;
        const int bt = tid >> 4;
        #pragma unroll
        for (int i = 0; i < 4; ++i) {
            const int b = bt + 16 * i;
            const float4 v = *reinterpret_cast<const float4*>(
                xall + ((size_t)(b * 12 + 11) * MN + n) * 64 + c4 * 4);
            xs[b * 65 + c4 * 4 + 0] = v.x;
            xs[b * 65 + c4 * 4 + 1] = v.y;
            xs[b * 65 + c4 * 4 + 2] = v.z;
            xs[b * 65 + c4 * 4 + 3] = v.w;
        }
    }
    __syncthreads();

    const int b  = tid & 63;
    const int t0 = tid >> 6;
    float a0 = 0.f, a1 = 0.f, a2 = 0.f;
    #pragma unroll
    for (int f = 0; f < 64; ++f) {
        const float x = xs[b * 65 + f];
        a0 += x * hs[t0 * 64 + f];
        a1 += x * hs[(t0 + 4) * 64 + f];
        a2 += x * hs[(t0 + 8) * 64 + f];
    }
    out[((size_t)(b * 12 + t0)) * MN + n]     = a0;
    out[((size_t)(b * 12 + t0 + 4)) * MN + n] = a1;
    out[((size_t)(b * 12 + t0 + 8)) * MN + n] = a2;
}

extern "C" void kernel_launch(void* const* d_in, const int* in_sizes, int n_in,
                              void* d_out, int out_size, void* d_ws, size_t ws_size,
                              hipStream_t stream)
{
    const float* xall = (const float*)d_in[0];
    const float* wts  = (const float*)d_in[1];
    const float* Whyp = (const float*)d_in[2];
    const float* bhyp = (const float*)d_in[3];
    float* out = (float*)d_out;

    const size_t slice  = (size_t)MN * HF * sizeof(float);          // 3 MB partial
    const size_t bf_sz  = (size_t)(8 + 6) * NKC * TILE_SH * 2;      // 132 MB bf16 tiles
    const int opts[8] = {16, 12, 8, 6, 4, 3, 2, 1};

    int ks_bf = 0;
    for (int i = 0; i < 8; ++i)
        if (bf_sz + (size_t)opts[i] * slice <= ws_size) { ks_bf = opts[i]; break; }

    if (ks_bf >= 4) {
        unsigned short* tiles = (unsigned short*)d_ws;
        unsigned short* Bbf   = tiles + (size_t)8 * NKC * TILE_SH;
        float* part = (float*)((char*)d_ws + bf_sz);
        const int NSTEP = NKC / ks_bf;

        convert_tiles<<<dim3(14 * NKC), dim3(256), 0, stream>>>(wts, Whyp, tiles);
        gemm_bf16<<<dim3(48 * ks_bf), dim3(512), 0, stream>>>(tiles, Bbf, part, NSTEP);
        h_reduce<<<dim3(768), dim3(256), 0, stream>>>(part, bhyp, ks_bf);
        hyper_out<<<dim3(1024), dim3(256), 0, stream>>>(xall, part, out);
    } else {
        float* part = (float*)d_ws;
        int ks = 1;
        for (int i = 0; i < 8; ++i)
            if ((size_t)opts[i] * slice <= ws_size) { ks = opts[i]; break; }
        const int KC = K2V / ks;
        gemm_h_split<<<dim3(48 * ks), dim3(512), 0, stream>>>(wts, Whyp, part, KC);
        h_reduce<<<dim3(768), dim3(256), 0, stream>>>(part, bhyp, ks);
        hyper_out<<<dim3(1024), dim3(256), 0, stream>>>(xall, part, out);
    }
}